// Round 1
// baseline (136.499 us; speedup 1.0000x reference)
//
#include <hip/hip_runtime.h>
#include <math.h>

// Problem constants (reference: B,D,E,H = 4,128,512,512)
#define BATCH 4
#define DDIM  128
#define EDIM  512
#define HDIM  512

// ---------------------------------------------------------------------------
// GEMM (NT): C[z][m][n] = sum_k A[z*sA + m*K + k] * B[z*sB + n*K + k]
// Both operands read row-wise (contiguous in k). 64x64 tile, BK=16,
// 256 threads, 4x4 outputs/thread, +1-padded LDS to break bank conflicts.
// ---------------------------------------------------------------------------
__global__ __launch_bounds__(256)
void gemm_nt(const float* __restrict__ A, long sA,
             const float* __restrict__ B, long sB,
             float* __restrict__ C, long sC,
             int M, int N, int K) {
    __shared__ float As[16][65];
    __shared__ float Bs[16][65];
    const int t  = threadIdx.x;
    const int m0 = blockIdx.y * 64, n0 = blockIdx.x * 64;
    const float* Ab = A + (long)blockIdx.z * sA;
    const float* Bb = B + (long)blockIdx.z * sB;
    float*       Cb = C + (long)blockIdx.z * sC;

    const int lr = t >> 2;        // 0..63: tile row to load
    const int lk = (t & 3) << 2;  // 0,4,8,12: k offset (float4)
    const int ty = t >> 4, tx = t & 15;

    float acc[4][4] = {};
    for (int k0 = 0; k0 < K; k0 += 16) {
        float4 av = *(const float4*)(Ab + (long)(m0 + lr) * K + k0 + lk);
        float4 bv = *(const float4*)(Bb + (long)(n0 + lr) * K + k0 + lk);
        As[lk + 0][lr] = av.x; As[lk + 1][lr] = av.y;
        As[lk + 2][lr] = av.z; As[lk + 3][lr] = av.w;
        Bs[lk + 0][lr] = bv.x; Bs[lk + 1][lr] = bv.y;
        Bs[lk + 2][lr] = bv.z; Bs[lk + 3][lr] = bv.w;
        __syncthreads();
        #pragma unroll
        for (int kk = 0; kk < 16; ++kk) {
            float a[4], b[4];
            #pragma unroll
            for (int i = 0; i < 4; ++i) a[i] = As[kk][ty * 4 + i];
            #pragma unroll
            for (int j = 0; j < 4; ++j) b[j] = Bs[kk][tx * 4 + j];
            #pragma unroll
            for (int i = 0; i < 4; ++i)
                #pragma unroll
                for (int j = 0; j < 4; ++j)
                    acc[i][j] = fmaf(a[i], b[j], acc[i][j]);
        }
        __syncthreads();
    }
    #pragma unroll
    for (int i = 0; i < 4; ++i) {
        float4 o = make_float4(acc[i][0], acc[i][1], acc[i][2], acc[i][3]);
        *(float4*)(Cb + (long)(m0 + ty * 4 + i) * N + n0 + tx * 4) = o;
    }
}

// ---------------------------------------------------------------------------
// Fused tanh-dot + masked log_softmax.
// One block per (b,d); 512 threads, one per e.
// decT: (B,D,H) row-major; encT: (B,H,E) (per-batch transposed so the
// per-h read encT[b][h][e] is lane-coalesced); mask: (B,E) bytes.
// ---------------------------------------------------------------------------
__device__ inline float fast_tanh(float x) {
    float ax = fabsf(x);
    float t  = __expf(-2.0f * ax);                         // in (0,1]
    float r  = (1.0f - t) * __builtin_amdgcn_rcpf(1.0f + t);
    return copysignf(r, x);
}

__global__ __launch_bounds__(512)
void attn_lsm(const float* __restrict__ decT,          // (B,D,H)
              const float* __restrict__ encT,          // (B,H,E)
              const unsigned char* __restrict__ mask,  // (B,E) bool bytes
              const float* __restrict__ vw,            // (H)
              float* __restrict__ out) {               // (B,D,E)
    const int bd = blockIdx.x;
    const int b  = bd / DDIM;
    const int e  = threadIdx.x;  // 0..511

    __shared__ float dec_s[HDIM];
    __shared__ float v_s[HDIM];
    __shared__ float red[8];

    dec_s[e] = decT[(long)bd * HDIM + e];
    v_s[e]   = vw[e];
    __syncthreads();

    const float* ecol = encT + (long)b * HDIM * EDIM + e;
    float acc = 0.f;
    #pragma unroll 8
    for (int h = 0; h < HDIM; ++h) {
        float x = dec_s[h] + ecol[(long)h * EDIM];
        acc = fmaf(fast_tanh(x), v_s[h], acc);
    }

    float val = mask[b * EDIM + e] ? -INFINITY : acc;

    const int wid = e >> 6, lid = e & 63;

    // --- block max ---
    float m = val;
    #pragma unroll
    for (int o = 32; o >= 1; o >>= 1) m = fmaxf(m, __shfl_xor(m, o));
    if (lid == 0) red[wid] = m;
    __syncthreads();
    m = red[0];
    #pragma unroll
    for (int i = 1; i < 8; ++i) m = fmaxf(m, red[i]);
    __syncthreads();  // red[] reused below

    // --- block sum of exp(val - m) ---
    float s = __expf(val - m);
    float ss = s;
    #pragma unroll
    for (int o = 32; o >= 1; o >>= 1) ss += __shfl_xor(ss, o);
    if (lid == 0) red[wid] = ss;
    __syncthreads();
    float tot = 0.f;
    #pragma unroll
    for (int i = 0; i < 8; ++i) tot += red[i];

    out[(long)bd * EDIM + e] = val - m - logf(tot);
}

// ---------------------------------------------------------------------------
extern "C" void kernel_launch(void* const* d_in, const int* in_sizes, int n_in,
                              void* d_out, int out_size, void* d_ws, size_t ws_size,
                              hipStream_t stream) {
    const float*         xdec = (const float*)d_in[0];         // (B,D,H)
    const float*         xenc = (const float*)d_in[1];         // (B,E,H)
    const unsigned char* mask = (const unsigned char*)d_in[2]; // (B,E)
    const float*         W1   = (const float*)d_in[3];         // (H,H)
    const float*         W2   = (const float*)d_in[4];         // (H,H)
    const float*         vw   = (const float*)d_in[5];         // (H)
    float*               out  = (float*)d_out;                 // (B,D,E)

    float* decT = (float*)d_ws;                                // B*D*H
    float* encT = decT + (size_t)BATCH * DDIM * HDIM;          // B*H*E

    // dec_t[b][d][h] = sum_k xdec[b,d,k] * W2[h,k]
    {
        dim3 grid(HDIM / 64, DDIM / 64, BATCH);  // (8, 2, 4)
        gemm_nt<<<grid, 256, 0, stream>>>(xdec, (long)DDIM * HDIM,
                                          W2, 0,
                                          decT, (long)DDIM * HDIM,
                                          DDIM, HDIM, HDIM);
    }
    // encT[b][h][e] = sum_k W1[h,k] * xenc[b,e,k]   (per-batch transposed)
    {
        dim3 grid(EDIM / 64, HDIM / 64, BATCH);  // (8, 8, 4)
        gemm_nt<<<grid, 256, 0, stream>>>(W1, 0,
                                          xenc, (long)EDIM * HDIM,
                                          encT, (long)HDIM * EDIM,
                                          HDIM, EDIM, HDIM);
    }

    attn_lsm<<<BATCH * DDIM, 512, 0, stream>>>(decT, encT, mask, vw, out);
}

// Round 2
// 74.554 us; speedup vs baseline: 1.8309x; 1.8309x over previous
//
#include <hip/hip_runtime.h>
#include <math.h>

// Problem constants (reference: B,D,E,H = 4,128,512,512)
#define BATCH 4
#define DDIM  128
#define EDIM  512
#define HDIM  512

// c = 2*log2(e): encT2/decT2 are pre-scaled by this so e^{2x} = exp2(dec2+enc2)
#define TANH_SCALE 2.8853900817779268f

typedef short short8v __attribute__((ext_vector_type(8)));
typedef float f32x4   __attribute__((ext_vector_type(4)));

#if defined(__has_builtin)
#  if __has_builtin(__builtin_amdgcn_exp2f)
#    define EXP2F(x) __builtin_amdgcn_exp2f(x)
#  endif
#endif
#ifndef EXP2F
#  define EXP2F(x) exp2f(x)
#endif
#define RCPF(x) __builtin_amdgcn_rcpf(x)

// fp32 -> bf16 bits, round-to-nearest-even (inputs are finite/sane)
static __device__ inline unsigned short f2bf(float f) {
    unsigned u = __float_as_uint(f);
    return (unsigned short)((u + 0x7FFFu + ((u >> 16) & 1u)) >> 16);
}

// ---------------------------------------------------------------------------
// MFMA bf16 GEMM (NT): C[z][m][n] = scale * sum_k A[z*sA+m*K+k] * B[z*sB+n*K+k]
// 64x64 tile, BK=32, 256 threads = 4 waves (2x2), each wave 32x32 (2x2 frags
// of 16x16x32). fp32 inputs converted to bf16 during LDS staging.
// ---------------------------------------------------------------------------
__global__ __launch_bounds__(256)
void gemm_bf16_nt(const float* __restrict__ A, long sA,
                  const float* __restrict__ B, long sB,
                  float* __restrict__ C, long sC,
                  int N, int K, float scale) {
    // pad to 40 shorts/row (80B): keeps 16B alignment for b128 ops, spreads banks
    __shared__ unsigned short As[64][40];
    __shared__ unsigned short Bs[64][40];

    const int t  = threadIdx.x;
    const int m0 = blockIdx.y * 64, n0 = blockIdx.x * 64;
    const float* Ab = A + (long)blockIdx.z * sA;
    const float* Bb = B + (long)blockIdx.z * sB;
    float*       Cb = C + (long)blockIdx.z * sC;

    const int srow = t >> 2;          // 0..63 staging row
    const int skq  = (t & 3) << 3;    // 0,8,16,24 staging k-offset

    const int wid = t >> 6;           // 0..3
    const int wm  = wid >> 1;         // 0..1
    const int wn  = wid & 1;          // 0..1
    const int l   = t & 63;
    const int lr  = l & 15;           // fragment row within 16
    const int lk  = (l >> 4) << 3;    // fragment k-offset (0,8,16,24)

    f32x4 acc[2][2] = {};

    for (int k0 = 0; k0 < K; k0 += 32) {
        // ---- stage A,B tiles (fp32 -> bf16) ----
        const float* ap = Ab + (long)(m0 + srow) * K + k0 + skq;
        const float* bp = Bb + (long)(n0 + srow) * K + k0 + skq;
        float4 a0 = *(const float4*)ap, a1 = *(const float4*)(ap + 4);
        float4 b0 = *(const float4*)bp, b1 = *(const float4*)(bp + 4);
        unsigned short* aw = &As[srow][skq];
        unsigned short* bw = &Bs[srow][skq];
        aw[0] = f2bf(a0.x); aw[1] = f2bf(a0.y); aw[2] = f2bf(a0.z); aw[3] = f2bf(a0.w);
        aw[4] = f2bf(a1.x); aw[5] = f2bf(a1.y); aw[6] = f2bf(a1.z); aw[7] = f2bf(a1.w);
        bw[0] = f2bf(b0.x); bw[1] = f2bf(b0.y); bw[2] = f2bf(b0.z); bw[3] = f2bf(b0.w);
        bw[4] = f2bf(b1.x); bw[5] = f2bf(b1.y); bw[6] = f2bf(b1.z); bw[7] = f2bf(b1.w);
        __syncthreads();

        // ---- fragments + MFMA ----
        short8v af[2], bf[2];
        #pragma unroll
        for (int fm = 0; fm < 2; ++fm)
            af[fm] = *(const short8v*)&As[wm * 32 + fm * 16 + lr][lk];
        #pragma unroll
        for (int fn = 0; fn < 2; ++fn)
            bf[fn] = *(const short8v*)&Bs[wn * 32 + fn * 16 + lr][lk];
        #pragma unroll
        for (int fm = 0; fm < 2; ++fm)
            #pragma unroll
            for (int fn = 0; fn < 2; ++fn)
                acc[fm][fn] = __builtin_amdgcn_mfma_f32_16x16x32_bf16(
                    af[fm], bf[fn], acc[fm][fn], 0, 0, 0);
        __syncthreads();
    }

    // ---- epilogue: D[row=(l>>4)*4+r][col=l&15], scaled ----
    const int crow = (l >> 4) << 2;
    #pragma unroll
    for (int fm = 0; fm < 2; ++fm)
        #pragma unroll
        for (int fn = 0; fn < 2; ++fn) {
            #pragma unroll
            for (int r = 0; r < 4; ++r) {
                int rr = m0 + wm * 32 + fm * 16 + crow + r;
                int cc = n0 + wn * 32 + fn * 16 + lr;
                Cb[(long)rr * N + cc] = scale * acc[fm][fn][r];
            }
        }
}

// ---------------------------------------------------------------------------
// Fused tanh-dot + masked log_softmax, 2 decoder rows per block.
// val_e = -sum_h 2*v[h] / (1 + exp2(dec2[h] + enc2[h][e]))   (shift-invariant
// equivalent of sum_h v[h]*tanh(...) under log_softmax).
// decT2: (B,D,H) pre-scaled by c; encT2: (B,H,E) pre-scaled by c.
// ---------------------------------------------------------------------------
__global__ __launch_bounds__(512)
void attn_lsm(const float* __restrict__ decT2,         // (B,D,H) * c
              const float* __restrict__ encT2,         // (B,H,E) * c
              const unsigned char* __restrict__ mask,  // (B,E)
              const float* __restrict__ vw,            // (H)
              float* __restrict__ out) {               // (B,D,E)
    const int p   = blockIdx.x;       // 0..255: (b, d-pair)
    const int bd0 = p * 2;
    const int b   = bd0 / DDIM;
    const int e   = threadIdx.x;      // 0..511

    __shared__ float2 dec_s[HDIM];    // {dec2[d0][h], dec2[d0+1][h]}
    __shared__ float  v2_s[HDIM];     // 2*v[h]
    __shared__ float  red0[8], red1[8];

    dec_s[e] = make_float2(decT2[(long)bd0 * HDIM + e],
                           decT2[(long)(bd0 + 1) * HDIM + e]);
    v2_s[e]  = 2.0f * vw[e];
    __syncthreads();

    const float* ec = encT2 + (long)b * HDIM * EDIM + e;
    float acc0 = 0.f, acc1 = 0.f;
    #pragma unroll 8
    for (int h = 0; h < HDIM; ++h) {
        float x  = ec[(long)h * EDIM];
        float2 d = dec_s[h];
        float v2 = v2_s[h];
        float t0 = EXP2F(d.x + x);
        float t1 = EXP2F(d.y + x);
        acc0 = fmaf(v2, RCPF(1.0f + t0), acc0);
        acc1 = fmaf(v2, RCPF(1.0f + t1), acc1);
    }

    const bool mk = mask[b * EDIM + e];
    float val0 = mk ? -INFINITY : -acc0;
    float val1 = mk ? -INFINITY : -acc1;

    const int wid = e >> 6, lid = e & 63;

    // --- block max (both channels) ---
    float m0 = val0, m1 = val1;
    #pragma unroll
    for (int o = 32; o >= 1; o >>= 1) {
        m0 = fmaxf(m0, __shfl_xor(m0, o));
        m1 = fmaxf(m1, __shfl_xor(m1, o));
    }
    if (lid == 0) { red0[wid] = m0; red1[wid] = m1; }
    __syncthreads();
    m0 = red0[0]; m1 = red1[0];
    #pragma unroll
    for (int i = 1; i < 8; ++i) { m0 = fmaxf(m0, red0[i]); m1 = fmaxf(m1, red1[i]); }
    __syncthreads();  // reuse red[]

    // --- block sum of exp(val - m) ---
    float s0 = __expf(val0 - m0), s1 = __expf(val1 - m1);
    #pragma unroll
    for (int o = 32; o >= 1; o >>= 1) {
        s0 += __shfl_xor(s0, o);
        s1 += __shfl_xor(s1, o);
    }
    if (lid == 0) { red0[wid] = s0; red1[wid] = s1; }
    __syncthreads();
    float tot0 = 0.f, tot1 = 0.f;
    #pragma unroll
    for (int i = 0; i < 8; ++i) { tot0 += red0[i]; tot1 += red1[i]; }

    out[(long)bd0 * EDIM + e]       = val0 - m0 - logf(tot0);
    out[(long)(bd0 + 1) * EDIM + e] = val1 - m1 - logf(tot1);
}

// ---------------------------------------------------------------------------
extern "C" void kernel_launch(void* const* d_in, const int* in_sizes, int n_in,
                              void* d_out, int out_size, void* d_ws, size_t ws_size,
                              hipStream_t stream) {
    const float*         xdec = (const float*)d_in[0];         // (B,D,H)
    const float*         xenc = (const float*)d_in[1];         // (B,E,H)
    const unsigned char* mask = (const unsigned char*)d_in[2]; // (B,E)
    const float*         W1   = (const float*)d_in[3];         // (H,H)
    const float*         W2   = (const float*)d_in[4];         // (H,H)
    const float*         vw   = (const float*)d_in[5];         // (H)
    float*               out  = (float*)d_out;                 // (B,D,E)

    float* decT2 = (float*)d_ws;                               // B*D*H
    float* encT2 = decT2 + (size_t)BATCH * DDIM * HDIM;        // B*H*E

    // decT2[b][d][o] = c * sum_k xdec[b,d,k] * W2[o,k]   (M=D, N=H)
    {
        dim3 grid(HDIM / 64, DDIM / 64, BATCH);  // (8, 2, 4)
        gemm_bf16_nt<<<grid, 256, 0, stream>>>(xdec, (long)DDIM * HDIM,
                                               W2, 0,
                                               decT2, (long)DDIM * HDIM,
                                               HDIM, HDIM, TANH_SCALE);
    }
    // encT2[b][o][e] = c * sum_k W1[o,k] * xenc[b,e,k]   (M=H, N=E, transposed out)
    {
        dim3 grid(EDIM / 64, HDIM / 64, BATCH);  // (8, 8, 4)
        gemm_bf16_nt<<<grid, 256, 0, stream>>>(W1, 0,
                                               xenc, (long)EDIM * HDIM,
                                               encT2, (long)HDIM * EDIM,
                                               EDIM, HDIM, TANH_SCALE);
    }

    attn_lsm<<<BATCH * DDIM / 2, 512, 0, stream>>>(decT2, encT2, mask, vw, out);
}

// Round 3
// 48.385 us; speedup vs baseline: 2.8211x; 1.5409x over previous
//
#include <hip/hip_runtime.h>
#include <math.h>

// Problem constants (reference: B,D,E,H = 4,128,512,512)
#define BATCH 4
#define DDIM  128
#define EDIM  512
#define HDIM  512

// c = 2*log2(e): P=exp2(c*dec_t), Q=exp2(c*enc_t) so e^{2(dec+enc)} = P*Q
#define TANH_SCALE 2.8853900817779268f

typedef short short8v __attribute__((ext_vector_type(8)));
typedef float f32x4   __attribute__((ext_vector_type(4)));

#define EXP2F(x) __builtin_amdgcn_exp2f(x)
#define RCPF(x)  __builtin_amdgcn_rcpf(x)

// fp32 -> bf16 bits, round-to-nearest-even (inputs are finite/sane)
static __device__ inline unsigned short f2bf(float f) {
    unsigned u = __float_as_uint(f);
    return (unsigned short)((u + 0x7FFFu + ((u >> 16) & 1u)) >> 16);
}

// ---------------------------------------------------------------------------
// Fused bf16-MFMA GEMM pair (NT), epilogue = exp2(c * acc):
//   blocks 0..63   : P[b,d,h] = exp2(c * sum_k xdec[b,d,k] * W2[h,k])
//   blocks 64..319 : Q[b,h,e] = exp2(c * sum_k W1[h,k]   * xenc[b,e,k])
// 64x64 tile, BK=32, 256 threads = 4 waves (2x2), wave = 2x2 frags of
// 16x16x32. Both tasks have K=512 and output row stride 512.
// ---------------------------------------------------------------------------
__global__ __launch_bounds__(256)
void gemm_both(const float* __restrict__ xdec, const float* __restrict__ W2,
               const float* __restrict__ xenc, const float* __restrict__ W1,
               float* __restrict__ P, float* __restrict__ Q) {
    __shared__ unsigned short As[64][40];  // 80B rows: 16B-aligned, bank-spread
    __shared__ unsigned short Bs[64][40];

    const int id = blockIdx.x;
    const float *Ab, *Bb;
    float* Cb;
    int m0, n0;
    if (id < 64) {                    // dec task: 4b x 2mb x 8nb
        int b = id >> 4, r = id & 15;
        m0 = (r >> 3) * 64; n0 = (r & 7) * 64;
        Ab = xdec + (long)b * DDIM * HDIM;
        Bb = W2;
        Cb = P + (long)b * DDIM * HDIM;
    } else {                          // enc task: 4b x 8mb(h) x 8nb(e)
        int t2 = id - 64;
        int b = t2 >> 6, r = t2 & 63;
        m0 = (r >> 3) * 64; n0 = (r & 7) * 64;
        Ab = W1;
        Bb = xenc + (long)b * EDIM * HDIM;
        Cb = Q + (long)b * HDIM * EDIM;
    }

    const int t    = threadIdx.x;
    const int srow = t >> 2;          // 0..63 staging row
    const int skq  = (t & 3) << 3;    // 0,8,16,24 staging k-offset

    const int wid = t >> 6;
    const int wm  = wid >> 1, wn = wid & 1;
    const int l   = t & 63;
    const int lr  = l & 15;           // fragment row within 16
    const int lk  = (l >> 4) << 3;    // fragment k-offset

    f32x4 acc[2][2] = {};

    const float* ap = Ab + (long)(m0 + srow) * HDIM + skq;
    const float* bp = Bb + (long)(n0 + srow) * HDIM + skq;

    for (int k0 = 0; k0 < HDIM; k0 += 32, ap += 32, bp += 32) {
        float4 a0 = *(const float4*)ap, a1 = *(const float4*)(ap + 4);
        float4 b0 = *(const float4*)bp, b1 = *(const float4*)(bp + 4);
        unsigned short* aw = &As[srow][skq];
        unsigned short* bw = &Bs[srow][skq];
        aw[0] = f2bf(a0.x); aw[1] = f2bf(a0.y); aw[2] = f2bf(a0.z); aw[3] = f2bf(a0.w);
        aw[4] = f2bf(a1.x); aw[5] = f2bf(a1.y); aw[6] = f2bf(a1.z); aw[7] = f2bf(a1.w);
        bw[0] = f2bf(b0.x); bw[1] = f2bf(b0.y); bw[2] = f2bf(b0.z); bw[3] = f2bf(b0.w);
        bw[4] = f2bf(b1.x); bw[5] = f2bf(b1.y); bw[6] = f2bf(b1.z); bw[7] = f2bf(b1.w);
        __syncthreads();

        short8v af[2], bf[2];
        #pragma unroll
        for (int fm = 0; fm < 2; ++fm)
            af[fm] = *(const short8v*)&As[wm * 32 + fm * 16 + lr][lk];
        #pragma unroll
        for (int fn = 0; fn < 2; ++fn)
            bf[fn] = *(const short8v*)&Bs[wn * 32 + fn * 16 + lr][lk];
        #pragma unroll
        for (int fm = 0; fm < 2; ++fm)
            #pragma unroll
            for (int fn = 0; fn < 2; ++fn)
                acc[fm][fn] = __builtin_amdgcn_mfma_f32_16x16x32_bf16(
                    af[fm], bf[fn], acc[fm][fn], 0, 0, 0);
        __syncthreads();
    }

    // epilogue: C[row=(l>>4)*4+r][col=l&15] = exp2(c * acc)
    const int crow = (l >> 4) << 2;
    #pragma unroll
    for (int fm = 0; fm < 2; ++fm)
        #pragma unroll
        for (int fn = 0; fn < 2; ++fn)
            #pragma unroll
            for (int r = 0; r < 4; ++r) {
                int rr = m0 + wm * 32 + fm * 16 + crow + r;
                int cc = n0 + wn * 32 + fn * 16 + lr;
                Cb[(long)rr * 512 + cc] = EXP2F(TANH_SCALE * acc[fm][fn][r]);
            }
}

// ---------------------------------------------------------------------------
// Fused tanh-dot + masked log_softmax, 2 decoder rows per block.
//   val_e = sum_h (-2 v[h]) * rcp(1 + P[d,h]*Q[h,e])
// (shift-invariant equivalent of sum_h v[h]*tanh(dec+enc) under log_softmax)
// ---------------------------------------------------------------------------
__global__ __launch_bounds__(512)
void attn_lsm(const float* __restrict__ P,             // (B,D,H) exp2-form
              const float* __restrict__ Q,             // (B,H,E) exp2-form
              const unsigned char* __restrict__ mask,  // (B,E)
              const float* __restrict__ vw,            // (H)
              float* __restrict__ out) {               // (B,D,E)
    const int p   = blockIdx.x;       // 0..255: (b, d-pair)
    const int bd0 = p * 2;
    const int b   = bd0 / DDIM;
    const int e   = threadIdx.x;      // 0..511

    __shared__ float2 dec_s[HDIM];    // {P[d0][h], P[d0+1][h]}
    __shared__ float  v2_s[HDIM];     // -2*v[h]
    __shared__ float  red0[8], red1[8];

    dec_s[e] = make_float2(P[(long)bd0 * HDIM + e],
                           P[(long)(bd0 + 1) * HDIM + e]);
    v2_s[e]  = -2.0f * vw[e];
    __syncthreads();

    const float* qp = Q + (long)b * HDIM * EDIM + e;
    float acc0 = 0.f, acc1 = 0.f;
    #pragma unroll 8
    for (int h = 0; h < HDIM; ++h, qp += EDIM) {
        float  q = *qp;
        float2 d = dec_s[h];
        float v2 = v2_s[h];
        acc0 = fmaf(v2, RCPF(fmaf(d.x, q, 1.0f)), acc0);
        acc1 = fmaf(v2, RCPF(fmaf(d.y, q, 1.0f)), acc1);
    }

    const bool mk = mask[b * EDIM + e];
    float val0 = mk ? -INFINITY : acc0;
    float val1 = mk ? -INFINITY : acc1;

    const int wid = e >> 6, lid = e & 63;

    // --- block max (both channels) ---
    float m0 = val0, m1 = val1;
    #pragma unroll
    for (int o = 32; o >= 1; o >>= 1) {
        m0 = fmaxf(m0, __shfl_xor(m0, o));
        m1 = fmaxf(m1, __shfl_xor(m1, o));
    }
    if (lid == 0) { red0[wid] = m0; red1[wid] = m1; }
    __syncthreads();
    m0 = red0[0]; m1 = red1[0];
    #pragma unroll
    for (int i = 1; i < 8; ++i) { m0 = fmaxf(m0, red0[i]); m1 = fmaxf(m1, red1[i]); }
    __syncthreads();  // reuse red[]

    // --- block sum of exp(val - m) ---
    float s0 = __expf(val0 - m0), s1 = __expf(val1 - m1);
    #pragma unroll
    for (int o = 32; o >= 1; o >>= 1) {
        s0 += __shfl_xor(s0, o);
        s1 += __shfl_xor(s1, o);
    }
    if (lid == 0) { red0[wid] = s0; red1[wid] = s1; }
    __syncthreads();
    float tot0 = 0.f, tot1 = 0.f;
    #pragma unroll
    for (int i = 0; i < 8; ++i) { tot0 += red0[i]; tot1 += red1[i]; }

    out[(long)bd0 * EDIM + e]       = val0 - m0 - __logf(tot0);
    out[(long)(bd0 + 1) * EDIM + e] = val1 - m1 - __logf(tot1);
}

// ---------------------------------------------------------------------------
extern "C" void kernel_launch(void* const* d_in, const int* in_sizes, int n_in,
                              void* d_out, int out_size, void* d_ws, size_t ws_size,
                              hipStream_t stream) {
    const float*         xdec = (const float*)d_in[0];         // (B,D,H)
    const float*         xenc = (const float*)d_in[1];         // (B,E,H)
    const unsigned char* mask = (const unsigned char*)d_in[2]; // (B,E)
    const float*         W1   = (const float*)d_in[3];         // (H,H)
    const float*         W2   = (const float*)d_in[4];         // (H,H)
    const float*         vw   = (const float*)d_in[5];         // (H)
    float*               out  = (float*)d_out;                 // (B,D,E)

    float* P = (float*)d_ws;                                   // B*D*H
    float* Q = P + (size_t)BATCH * DDIM * HDIM;                // B*H*E

    gemm_both<<<64 + 256, 256, 0, stream>>>(xdec, W2, xenc, W1, P, Q);
    attn_lsm<<<BATCH * DDIM / 2, 512, 0, stream>>>(P, Q, mask, vw, out);
}